// Round 1
// baseline (160.169 us; speedup 1.0000x reference)
//
#include <hip/hip_runtime.h>

#define BB 4
#define CC 16
#define TT 32
#define HWN 4096
#define NCH 4
#define CHN 1024

// ws layout (float offsets)
#define WS_BQ   0                                 // [B][C][2][HWN]      524288
#define WS_QTP  (WS_BQ + BB*CC*2*HWN)             // [B][C][NCH][6][TT]  49152
#define WS_KSP  (WS_QTP + BB*CC*NCH*6*TT)         // [B][C][NCH][8]      2048
#define WS_AQ   (WS_KSP + BB*CC*NCH*8)            // [B][C][2][TT]       4096
#define WS_CTX  (WS_AQ + BB*CC*2*TT)              // [B][C][2][2]        256

__device__ __forceinline__ float wsum64(float v){
#pragma unroll
  for (int m = 1; m < 64; m <<= 1) v += __shfl_xor(v, m, 64);
  return v;
}
__device__ __forceinline__ float wmax64(float v){
#pragma unroll
  for (int m = 1; m < 64; m <<= 1) v = fmaxf(v, __shfl_xor(v, m, 64));
  return v;
}
__device__ __forceinline__ float gsum16(float v){
  v += __shfl_xor(v, 1, 64);
  v += __shfl_xor(v, 2, 64);
  v += __shfl_xor(v, 4, 64);
  v += __shfl_xor(v, 8, 64);
  return v;
}

// K1: one block per (b,c,n-chunk). Reads x once. Produces:
//  - Bq[b][c][d][n] = sqrt(softmax_d(qs)+eps)
//  - qkv_t chunk partials
//  - ks softmax chunk stats (max, sumexp, T[e][d]=sum sqrt(exp(ks-M))*sqrt(vs))
__global__ __launch_bounds__(256) void k1_stage(const float* __restrict__ x,
    const float* __restrict__ wqs, const float* __restrict__ wqt,
    float* __restrict__ ws)
{
  const int bx = blockIdx.x;
  const int ch = bx & (NCH-1);
  const int c  = (bx >> 2) & (CC-1);
  const int b  = bx >> 6;
  const int tid  = threadIdx.x;
  const int wave = tid >> 6;
  const int lane = tid & 63;

  __shared__ float qtw[16][6][TT];   // 16-lane-group partials of qkv_t
  __shared__ float red[4][8];
  __shared__ float bcast[2];

  const int n0 = ch*CHN + tid*4;
  const float* xrow = x + ((size_t)(b*CC + c))*TT*HWN + n0;

  // w_qkv_t values for this thread's 4 columns (t-invariant)
  float4 wt4[6];
#pragma unroll
  for (int k = 0; k < 6; ++k)
    wt4[k] = *(const float4*)(wqt + k*HWN + n0);

  float accs[6][4];
#pragma unroll
  for (int k = 0; k < 6; ++k){
    accs[k][0]=0.f; accs[k][1]=0.f; accs[k][2]=0.f; accs[k][3]=0.f;
  }

  float4 xv = *(const float4*)(xrow);
  for (int t = 0; t < TT; ++t){
    float4 nxt = xv;
    if (t+1 < TT) nxt = *(const float4*)(xrow + (size_t)(t+1)*HWN);   // prefetch
#pragma unroll
    for (int k = 0; k < 6; ++k){
      const float w = wqs[k*TT + t];
      accs[k][0] = fmaf(xv.x, w, accs[k][0]);
      accs[k][1] = fmaf(xv.y, w, accs[k][1]);
      accs[k][2] = fmaf(xv.z, w, accs[k][2]);
      accs[k][3] = fmaf(xv.w, w, accs[k][3]);
      float p = xv.x*wt4[k].x + xv.y*wt4[k].y + xv.z*wt4[k].z + xv.w*wt4[k].w;
      p = gsum16(p);                          // sum over 16-lane group
      if ((lane & 15) == 0) qtw[wave*4 + (lane>>4)][k][t] = p;
    }
    xv = nxt;
  }

  const float eps = 1e-10f;

  // qs softmax over d (local per n) -> Bq
  {
    float o0[4], o1[4];
#pragma unroll
    for (int j = 0; j < 4; ++j){
      float d0 = accs[0][j], d1 = accs[1][j];
      float mm = fmaxf(d0, d1);
      float e0 = __expf(d0-mm), e1 = __expf(d1-mm);
      float inv = 1.f/(e0+e1);
      o0[j] = sqrtf(e0*inv + eps);
      o1[j] = sqrtf(e1*inv + eps);
    }
    float* bqp = ws + WS_BQ + ((size_t)((b*CC+c)*2))*HWN + n0;
    *(float4*)(bqp)       = make_float4(o0[0],o0[1],o0[2],o0[3]);
    *(float4*)(bqp + HWN) = make_float4(o1[0],o1[1],o1[2],o1[3]);
  }

  // ks chunk max
  float m0 = fmaxf(fmaxf(accs[2][0],accs[2][1]), fmaxf(accs[2][2],accs[2][3]));
  float m1 = fmaxf(fmaxf(accs[3][0],accs[3][1]), fmaxf(accs[3][2],accs[3][3]));
  m0 = wmax64(m0); m1 = wmax64(m1);
  if (lane == 0){ red[wave][0] = m0; red[wave][1] = m1; }
  __syncthreads();
  if (tid == 0){
    bcast[0] = fmaxf(fmaxf(red[0][0],red[1][0]), fmaxf(red[2][0],red[3][0]));
    bcast[1] = fmaxf(fmaxf(red[0][1],red[1][1]), fmaxf(red[2][1],red[3][1]));
  }
  __syncthreads();
  const float M0 = bcast[0], M1 = bcast[1];

  float z0=0,z1=0,t00=0,t01=0,t10=0,t11=0;   // t[e][d]
#pragma unroll
  for (int j = 0; j < 4; ++j){
    float e0 = __expf(accs[2][j]-M0);
    float e1 = __expf(accs[3][j]-M1);
    z0 += e0; z1 += e1;
    float s0 = sqrtf(e0), s1 = sqrtf(e1);
    float v0 = sqrtf(accs[4][j]), v1 = sqrtf(accs[5][j]);
    t00 = fmaf(s0, v0, t00);
    t01 = fmaf(s1, v0, t01);
    t10 = fmaf(s0, v1, t10);
    t11 = fmaf(s1, v1, t11);
  }
  z0 = wsum64(z0);  z1 = wsum64(z1);
  t00 = wsum64(t00); t01 = wsum64(t01); t10 = wsum64(t10); t11 = wsum64(t11);
  if (lane == 0){
    red[wave][2]=z0; red[wave][3]=z1;
    red[wave][4]=t00; red[wave][5]=t01; red[wave][6]=t10; red[wave][7]=t11;
  }
  __syncthreads();
  if (tid < 8){
    float s;
    if (tid < 2) s = bcast[tid];
    else         s = red[0][tid]+red[1][tid]+red[2][tid]+red[3][tid];
    ws[WS_KSP + ((size_t)((b*CC+c)*NCH + ch))*8 + tid] = s;
  }

  // fold 16 group-partials of qkv_t -> chunk partial
  if (tid < 192){
    const int k = tid / 32, t = tid & 31;
    float s = 0.f;
#pragma unroll
    for (int g = 0; g < 16; ++g) s += qtw[g][k][t];
    ws[WS_QTP + ((size_t)(((b*CC+c)*NCH + ch)*6 + k))*TT + t] = s;
  }
}

// K2: one block (1 wave) per (b,c): combine partials -> Aq, ctx
__global__ __launch_bounds__(64) void k2_combine(float* __restrict__ ws)
{
  const int bc_ = blockIdx.x;      // b*CC + c
  const int tid = threadIdx.x;
  __shared__ float qt[6][TT];
  const float eps = 1e-10f;
  const float scale = 0.8408964152537145f;   // KD^-0.25

  for (int i = tid; i < 192; i += 64){
    const int k = i / 32, t = i & 31;
    float s = 0.f;
#pragma unroll
    for (int ch = 0; ch < NCH; ++ch)
      s += ws[WS_QTP + ((size_t)((bc_*NCH + ch)*6 + k))*TT + t];
    qt[k][t] = s;
  }
  __syncthreads();

  if (tid < TT){
    const int t = tid;
    float q0 = qt[0][t], q1 = qt[1][t];
    float mm = fmaxf(q0,q1);
    float e0 = __expf(q0-mm), e1 = __expf(q1-mm);
    float inv = 1.f/(e0+e1);
    ws[WS_AQ + (bc_*2+0)*TT + t] = sqrtf(e0*inv + eps);
    ws[WS_AQ + (bc_*2+1)*TT + t] = sqrtf(e1*inv + eps);
  }
  if (tid < 2){
    const int d = tid;
    // kt softmax over t + St[e]
    float M = -1e30f;
    for (int t = 0; t < TT; ++t) M = fmaxf(M, qt[2+d][t]);
    float Z = 0.f;
    for (int t = 0; t < TT; ++t) Z += __expf(qt[2+d][t]-M);
    const float invZ = 1.f/Z;
    float St0 = 0.f, St1 = 0.f;
    for (int t = 0; t < TT; ++t){
      float p = __expf(qt[2+d][t]-M)*invZ;
      float r = sqrtf(p + eps);
      St0 += r*sqrtf(qt[4][t]);
      St1 += r*sqrtf(qt[5][t]);
    }
    // Sn[e] from chunk stats
    const float* kp = ws + WS_KSP + (size_t)bc_*NCH*8;
    float M2 = -1e30f;
    for (int ch = 0; ch < NCH; ++ch) M2 = fmaxf(M2, kp[ch*8+d]);
    float Z2 = 0.f, Sn0 = 0.f, Sn1 = 0.f;
    for (int ch = 0; ch < NCH; ++ch){
      const float mc = kp[ch*8+d];
      Z2  += kp[ch*8+2+d]*__expf(mc-M2);
      const float hw = __expf((mc-M2)*0.5f);
      Sn0 += kp[ch*8+4+d]*hw;
      Sn1 += kp[ch*8+6+d]*hw;
    }
    const float invsZ = rsqrtf(Z2);
    Sn0 *= invsZ; Sn1 *= invsZ;
    ws[WS_CTX + (bc_*2+d)*2+0] = scale*St0*Sn0;
    ws[WS_CTX + (bc_*2+d)*2+1] = scale*St1*Sn1;
  }
}

// K3: one block per (b,t,n-chunk of 1024). y = sqrt((Cs@Bq)*(Ct@Bq))
__global__ __launch_bounds__(256) void k3_out(const float* __restrict__ ws,
    const float* __restrict__ wos, const float* __restrict__ wot,
    float* __restrict__ out)
{
  const int bx = blockIdx.x;
  const int ch = bx & 3;
  const int t  = (bx >> 2) & (TT-1);
  const int b  = bx >> 7;
  const int tid = threadIdx.x;

  __shared__ float4 Cs4[CC][8];
  __shared__ float4 Ct4[CC][8];
  const float scale = 0.8408964152537145f;

  for (int i = tid; i < 512; i += 256){
    const int c = i >> 5, m = i & 31, cp = m >> 1, d = m & 1;
    const float* ctxp = ws + WS_CTX + ((b*CC+cp)*2+d)*2;
    const float c0 = ctxp[0], c1 = ctxp[1];
    const float aq = ws[WS_AQ + ((b*CC+cp)*2+d)*TT + t];
    const float f = scale * aq;
    ((float*)Cs4)[i] = f*(wos[c*32 + cp*2+0]*c0 + wos[c*32 + cp*2+1]*c1);
    ((float*)Ct4)[i] = f*(wot[c*32 + cp*2+0]*c0 + wot[c*32 + cp*2+1]*c1);
  }
  __syncthreads();

  const int n0 = ch*1024 + tid*4;
  const float* bqbase = ws + WS_BQ + ((size_t)(b*CC*2))*HWN + n0;
  float4 bq[32];
#pragma unroll
  for (int m = 0; m < 32; ++m)
    bq[m] = *(const float4*)(bqbase + (size_t)m*HWN);

  float* outp = out + (((size_t)(b*CC))*TT + t)*HWN + n0;
#pragma unroll 1
  for (int c = 0; c < CC; ++c){
    float4 aS = make_float4(0,0,0,0), aT = make_float4(0,0,0,0);
#pragma unroll
    for (int mm = 0; mm < 8; ++mm){
      const float4 cs = Cs4[c][mm];
      const float4 ct = Ct4[c][mm];
      const float4 b0 = bq[mm*4+0], b1 = bq[mm*4+1], b2 = bq[mm*4+2], b3 = bq[mm*4+3];
      aS.x += cs.x*b0.x + cs.y*b1.x + cs.z*b2.x + cs.w*b3.x;
      aS.y += cs.x*b0.y + cs.y*b1.y + cs.z*b2.y + cs.w*b3.y;
      aS.z += cs.x*b0.z + cs.y*b1.z + cs.z*b2.z + cs.w*b3.z;
      aS.w += cs.x*b0.w + cs.y*b1.w + cs.z*b2.w + cs.w*b3.w;
      aT.x += ct.x*b0.x + ct.y*b1.x + ct.z*b2.x + ct.w*b3.x;
      aT.y += ct.x*b0.y + ct.y*b1.y + ct.z*b2.y + ct.w*b3.y;
      aT.z += ct.x*b0.z + ct.y*b1.z + ct.z*b2.z + ct.w*b3.z;
      aT.w += ct.x*b0.w + ct.y*b1.w + ct.z*b2.w + ct.w*b3.w;
    }
    float4 y;
    y.x = sqrtf(aS.x*aT.x);
    y.y = sqrtf(aS.y*aT.y);
    y.z = sqrtf(aS.z*aT.z);
    y.w = sqrtf(aS.w*aT.w);
    *(float4*)(outp + (size_t)c*TT*HWN) = y;
  }
}

extern "C" void kernel_launch(void* const* d_in, const int* in_sizes, int n_in,
                              void* d_out, int out_size, void* d_ws, size_t ws_size,
                              hipStream_t stream)
{
  const float* x   = (const float*)d_in[0];
  const float* wqs = (const float*)d_in[1];
  const float* wqt = (const float*)d_in[2];
  const float* wos = (const float*)d_in[3];
  const float* wot = (const float*)d_in[4];
  float* out = (float*)d_out;
  float* ws  = (float*)d_ws;

  hipLaunchKernelGGL(k1_stage, dim3(BB*CC*NCH), dim3(256), 0, stream, x, wqs, wqt, ws);
  hipLaunchKernelGGL(k2_combine, dim3(BB*CC), dim3(64), 0, stream, ws);
  hipLaunchKernelGGL(k3_out, dim3(BB*TT*4), dim3(256), 0, stream, ws, wos, wot, out);
}